// Round 1
// baseline (993.048 us; speedup 1.0000x reference)
//
#include <hip/hip_runtime.h>

// Problem constants (reference: B=16, C=256, W=H=32, HEADS=4)
constexpr int Bb   = 16;
constexpr int Cch  = 256;
constexpr int NH   = 4;
constexpr int Dh   = 64;     // C / HEADS
constexpr int Nn   = 1024;   // W*H
constexpr int BI   = 32;     // query tile
constexpr int BJ   = 32;     // key tile

// ---------------------------------------------------------------------------
// Projection: y[b,o,n] = sum_c W[o,c] * x[b,c,n] + bias[o]
// One block computes a 64(o) x 64(n) tile for one (b, proj).
// grid = (N/64, C/64, 3*B), block = 256 (16x16 threads, 4x4 micro-tile each)
// ---------------------------------------------------------------------------
__global__ __launch_bounds__(256) void proj_kernel(
    const float* __restrict__ x,
    const float* __restrict__ Wq, const float* __restrict__ bq,
    const float* __restrict__ Wk, const float* __restrict__ bk,
    const float* __restrict__ Wv, const float* __restrict__ bv,
    float* __restrict__ qo, float* __restrict__ ko, float* __restrict__ vo)
{
    const int n0 = blockIdx.x * 64;
    const int o0 = blockIdx.y * 64;
    const int z  = blockIdx.z;
    const int p  = z % 3;           // 0=q, 1=k, 2=v
    const int b  = z / 3;

    const float* W    = (p == 0) ? Wq : (p == 1) ? Wk : Wv;
    const float* bias = (p == 0) ? bq : (p == 1) ? bk : bv;
    float*       y    = (p == 0) ? qo : (p == 1) ? ko : vo;

    __shared__ float Ws[64][65];   // [o][c], +1 pad
    __shared__ float Xs[64][68];   // [c][n], +4 pad so rows stay 16B-aligned

    const int t  = threadIdx.x;
    const int to = t >> 4;   // 0..15  (o direction)
    const int tn = t & 15;   // 0..15  (n direction)

    float4 acc[4];
    #pragma unroll
    for (int i = 0; i < 4; i++) acc[i] = make_float4(0.f, 0.f, 0.f, 0.f);

    for (int c0 = 0; c0 < Cch; c0 += 64) {
        #pragma unroll
        for (int l = 0; l < 16; l++) {
            int e  = t + l * 256;
            int r  = e >> 6;
            int cc = e & 63;
            Ws[r][cc] = W[(o0 + r) * Cch + (c0 + cc)];
            Xs[r][cc] = x[((size_t)b * Cch + (c0 + r)) * Nn + (n0 + cc)];
        }
        __syncthreads();

        #pragma unroll 16
        for (int cc = 0; cc < 64; cc++) {
            const float a0 = Ws[to * 4 + 0][cc];
            const float a1 = Ws[to * 4 + 1][cc];
            const float a2 = Ws[to * 4 + 2][cc];
            const float a3 = Ws[to * 4 + 3][cc];
            const float4 xv = *reinterpret_cast<const float4*>(&Xs[cc][tn * 4]);
            acc[0].x += a0 * xv.x; acc[0].y += a0 * xv.y; acc[0].z += a0 * xv.z; acc[0].w += a0 * xv.w;
            acc[1].x += a1 * xv.x; acc[1].y += a1 * xv.y; acc[1].z += a1 * xv.z; acc[1].w += a1 * xv.w;
            acc[2].x += a2 * xv.x; acc[2].y += a2 * xv.y; acc[2].z += a2 * xv.z; acc[2].w += a2 * xv.w;
            acc[3].x += a3 * xv.x; acc[3].y += a3 * xv.y; acc[3].z += a3 * xv.z; acc[3].w += a3 * xv.w;
        }
        __syncthreads();
    }

    #pragma unroll
    for (int oi = 0; oi < 4; oi++) {
        const int o = o0 + to * 4 + oi;
        const float bb = bias[o];
        float4 r = acc[oi];
        r.x += bb; r.y += bb; r.z += bb; r.w += bb;
        *reinterpret_cast<float4*>(&y[((size_t)b * Cch + o) * Nn + n0 + tn * 4]) = r;
    }
}

// ---------------------------------------------------------------------------
// rel[h][d][w*32 + hh] = rel_h[h][d][hh] + rel_w[h][d][w]
// ---------------------------------------------------------------------------
__global__ __launch_bounds__(256) void rel_kernel(
    const float* __restrict__ rel_h, const float* __restrict__ rel_w,
    float* __restrict__ rel)
{
    const int idx = blockIdx.x * 256 + threadIdx.x;   // over NH*Dh*Nn = 262144
    const int n   = idx & (Nn - 1);
    const int hd  = idx >> 10;        // h*64 + d
    const int ww  = n >> 5;
    const int hh  = n & 31;
    rel[idx] = rel_h[hd * 32 + hh] + rel_w[hd * 32 + ww];
}

// ---------------------------------------------------------------------------
// Flash-style attention per (b, h, 32-query tile).
// S[i,j] = sum_d q[d,i]*k[d,j] + rel[d,i]*q[d,j]; softmax over j;
// out[d,i] = sum_j P[i,j]*v[d,j].
// block = 256 threads.
// ---------------------------------------------------------------------------
__global__ __launch_bounds__(256) void attn_kernel(
    const float* __restrict__ q, const float* __restrict__ k,
    const float* __restrict__ v, const float* __restrict__ rel,
    float* __restrict__ out)
{
    const int i0 = blockIdx.x * BI;
    const int h  = blockIdx.y;
    const int b  = blockIdx.z;

    const float* qbh = q + (size_t)(b * NH + h) * Dh * Nn;   // [D][N]
    const float* kbh = k + (size_t)(b * NH + h) * Dh * Nn;
    const float* vbh = v + (size_t)(b * NH + h) * Dh * Nn;
    const float* rh  = rel + (size_t)h * Dh * Nn;

    __shared__ float qi[Dh][BI];        // 8 KB
    __shared__ float ri[Dh][BI];        // 8 KB
    __shared__ float kj[Dh][BJ];        // 8 KB
    __shared__ float qj[Dh][BJ];        // 8 KB
    __shared__ float vj[Dh][BJ];        // 8 KB
    __shared__ float Pt[BI][BJ + 4];    // +4 pad keeps rows 16B aligned
    __shared__ float mrow[BI], lrow[BI], arow[BI];

    const int t = threadIdx.x;

    // stage q_i / rel_i tiles
    for (int idx = t; idx < Dh * BI; idx += 256) {
        const int d  = idx >> 5;
        const int ii = idx & 31;
        qi[d][ii] = qbh[d * Nn + i0 + ii];
        ri[d][ii] = rh[d * Nn + i0 + ii];
    }
    if (t < BI) { mrow[t] = -1e30f; lrow[t] = 0.f; arow[t] = 1.f; }

    // score-phase mapping: 8 threads per row
    const int si = t >> 3;           // row 0..31
    const int sj = (t & 7) * 4;      // col base 0,4,...,28
    // O-phase mapping: thread owns (row oi, 8 d's starting at od)
    const int oi = t & 31;
    const int od = (t >> 5) * 8;

    float Oacc[8];
    #pragma unroll
    for (int u = 0; u < 8; u++) Oacc[u] = 0.f;

    for (int j0 = 0; j0 < Nn; j0 += BJ) {
        // stage k, q_j, v tiles
        for (int idx = t; idx < Dh * BJ; idx += 256) {
            const int d  = idx >> 5;
            const int jj = idx & 31;
            kj[d][jj] = kbh[d * Nn + j0 + jj];
            qj[d][jj] = qbh[d * Nn + j0 + jj];
            vj[d][jj] = vbh[d * Nn + j0 + jj];
        }
        __syncthreads();

        // ---- scores: 4 entries per thread ----
        float4 s = make_float4(0.f, 0.f, 0.f, 0.f);
        #pragma unroll 8
        for (int d = 0; d < Dh; d++) {
            const float a = qi[d][si];
            const float r = ri[d][si];
            const float4 kv = *reinterpret_cast<const float4*>(&kj[d][sj]);
            const float4 qv = *reinterpret_cast<const float4*>(&qj[d][sj]);
            s.x += a * kv.x + r * qv.x;
            s.y += a * kv.y + r * qv.y;
            s.z += a * kv.z + r * qv.z;
            s.w += a * kv.w + r * qv.w;
        }

        // row max over this tile (8 lanes per row, lane bits 0..2)
        float tm = fmaxf(fmaxf(s.x, s.y), fmaxf(s.z, s.w));
        tm = fmaxf(tm, __shfl_xor(tm, 1));
        tm = fmaxf(tm, __shfl_xor(tm, 2));
        tm = fmaxf(tm, __shfl_xor(tm, 4));

        const float mold = mrow[si];
        const float mnew = fmaxf(mold, tm);

        float4 pv;
        pv.x = __expf(s.x - mnew);
        pv.y = __expf(s.y - mnew);
        pv.z = __expf(s.z - mnew);
        pv.w = __expf(s.w - mnew);

        float ls = pv.x + pv.y + pv.z + pv.w;
        ls += __shfl_xor(ls, 1);
        ls += __shfl_xor(ls, 2);
        ls += __shfl_xor(ls, 4);

        if ((t & 7) == 0) {
            const float alpha = __expf(mold - mnew);
            arow[si] = alpha;
            mrow[si] = mnew;
            lrow[si] = lrow[si] * alpha + ls;
        }
        *reinterpret_cast<float4*>(&Pt[si][sj]) = pv;
        __syncthreads();

        // ---- O update ----
        const float alpha = arow[oi];
        #pragma unroll
        for (int u = 0; u < 8; u++) Oacc[u] *= alpha;

        float4 prow[8];
        const float4* prp = reinterpret_cast<const float4*>(&Pt[oi][0]);
        #pragma unroll
        for (int m = 0; m < 8; m++) prow[m] = prp[m];

        #pragma unroll
        for (int u = 0; u < 8; u++) {
            const float4* vr = reinterpret_cast<const float4*>(&vj[od + u][0]);
            float acc = 0.f;
            #pragma unroll
            for (int m = 0; m < 8; m++) {
                const float4 vv = vr[m];
                acc += prow[m].x * vv.x + prow[m].y * vv.y
                     + prow[m].z * vv.z + prow[m].w * vv.w;
            }
            Oacc[u] += acc;
        }
        __syncthreads();   // protect kj/qj/vj/Pt before next stage
    }

    const float inv = 1.0f / lrow[oi];
    #pragma unroll
    for (int u = 0; u < 8; u++) {
        const int d = od + u;
        out[((size_t)(b * Cch) + h * Dh + d) * Nn + i0 + oi] = Oacc[u] * inv;
    }
}

// ---------------------------------------------------------------------------
extern "C" void kernel_launch(void* const* d_in, const int* in_sizes, int n_in,
                              void* d_out, int out_size, void* d_ws, size_t ws_size,
                              hipStream_t stream)
{
    const float* x     = (const float*)d_in[0];
    const float* Wq    = (const float*)d_in[1];
    const float* bq    = (const float*)d_in[2];
    const float* Wk    = (const float*)d_in[3];
    const float* bk    = (const float*)d_in[4];
    const float* Wv    = (const float*)d_in[5];
    const float* bv    = (const float*)d_in[6];
    const float* rel_h = (const float*)d_in[7];
    const float* rel_w = (const float*)d_in[8];

    float* ws  = (float*)d_ws;
    float* q   = ws;                                   // B*C*N = 4,194,304 floats
    float* kk  = ws + (size_t)Bb * Cch * Nn;           // +4,194,304
    float* vv  = ws + (size_t)2 * Bb * Cch * Nn;       // +4,194,304
    float* rel = ws + (size_t)3 * Bb * Cch * Nn;       // NH*Dh*Nn = 262,144
    // total ws: ~51.4 MB

    proj_kernel<<<dim3(Nn / 64, Cch / 64, 3 * Bb), 256, 0, stream>>>(
        x, Wq, bq, Wk, bk, Wv, bv, q, kk, vv);
    rel_kernel<<<dim3((NH * Dh * Nn) / 256), 256, 0, stream>>>(rel_h, rel_w, rel);
    attn_kernel<<<dim3(Nn / BI, NH, Bb), 256, 0, stream>>>(
        q, kk, vv, rel, (float*)d_out);
}

// Round 3
// 255.573 us; speedup vs baseline: 3.8856x; 3.8856x over previous
//
#include <hip/hip_runtime.h>

// B=16, C=256, HEADS=4, d=64, N=W*H=1024
constexpr int Bb  = 16;
constexpr int Cch = 256;
constexpr int NH  = 4;
constexpr int Dh  = 64;
constexpr int Nn  = 1024;
constexpr int BI  = 64;     // query rows per block (4 waves x 16)
constexpr int BJ  = 64;     // key tile

typedef _Float16 f16;
typedef __attribute__((ext_vector_type(8))) _Float16 f16x8;
typedef __attribute__((ext_vector_type(4))) _Float16 f16x4;
typedef __attribute__((ext_vector_type(4))) float    f32x4;

__device__ inline float fc(const float4& v, int i) {
    return i == 0 ? v.x : i == 1 ? v.y : i == 2 ? v.z : v.w;
}

// ---------------------------------------------------------------------------
// Projection (fp32 math, fp16 output in attention-ready layouts):
//   p=0 (q), p=1 (k): y_t[b][h][n][d]  (transposed, fp16)
//   p=2 (v):          v_b[b][o][n]     (fp16, row-major)
// grid = (N/64, C/64, 3*B), block = 256
// ---------------------------------------------------------------------------
__global__ __launch_bounds__(256) void proj_kernel(
    const float* __restrict__ x,
    const float* __restrict__ Wq, const float* __restrict__ bq,
    const float* __restrict__ Wk, const float* __restrict__ bk,
    const float* __restrict__ Wv, const float* __restrict__ bv,
    f16* __restrict__ qt, f16* __restrict__ kt, f16* __restrict__ vb)
{
    const int n0 = blockIdx.x * 64;
    const int o0 = blockIdx.y * 64;        // == h*64, tile spans one head
    const int z  = blockIdx.z;
    const int p  = z % 3;
    const int b  = z / 3;

    const float* W    = (p == 0) ? Wq : (p == 1) ? Wk : Wv;
    const float* bias = (p == 0) ? bq : (p == 1) ? bk : bv;

    __shared__ float Ws[64][65];
    __shared__ float Xs[64][68];

    const int t  = threadIdx.x;
    const int to = t >> 4;   // 0..15
    const int tn = t & 15;   // 0..15

    float4 acc[4];
    #pragma unroll
    for (int i = 0; i < 4; i++) acc[i] = make_float4(0.f, 0.f, 0.f, 0.f);

    for (int c0 = 0; c0 < Cch; c0 += 64) {
        #pragma unroll
        for (int l = 0; l < 16; l++) {
            int e  = t + l * 256;
            int r  = e >> 6;
            int cc = e & 63;
            Ws[r][cc] = W[(o0 + r) * Cch + (c0 + cc)];
            Xs[r][cc] = x[((size_t)b * Cch + (c0 + r)) * Nn + (n0 + cc)];
        }
        __syncthreads();
        #pragma unroll 16
        for (int cc = 0; cc < 64; cc++) {
            const float a0 = Ws[to * 4 + 0][cc];
            const float a1 = Ws[to * 4 + 1][cc];
            const float a2 = Ws[to * 4 + 2][cc];
            const float a3 = Ws[to * 4 + 3][cc];
            const float4 xv = *reinterpret_cast<const float4*>(&Xs[cc][tn * 4]);
            acc[0].x += a0 * xv.x; acc[0].y += a0 * xv.y; acc[0].z += a0 * xv.z; acc[0].w += a0 * xv.w;
            acc[1].x += a1 * xv.x; acc[1].y += a1 * xv.y; acc[1].z += a1 * xv.z; acc[1].w += a1 * xv.w;
            acc[2].x += a2 * xv.x; acc[2].y += a2 * xv.y; acc[2].z += a2 * xv.z; acc[2].w += a2 * xv.w;
            acc[3].x += a3 * xv.x; acc[3].y += a3 * xv.y; acc[3].z += a3 * xv.z; acc[3].w += a3 * xv.w;
        }
        __syncthreads();
    }

    const float b0 = bias[o0 + to * 4 + 0];
    const float b1 = bias[o0 + to * 4 + 1];
    const float b2 = bias[o0 + to * 4 + 2];
    const float b3 = bias[o0 + to * 4 + 3];

    if (p == 2) {
        // v_b[b][o][n] fp16, 8B stores
        #pragma unroll
        for (int oi = 0; oi < 4; oi++) {
            const int o = o0 + to * 4 + oi;
            const float bb = fc(make_float4(b0, b1, b2, b3), oi);
            f16x4 w;
            w.x = (f16)(acc[oi].x + bb); w.y = (f16)(acc[oi].y + bb);
            w.z = (f16)(acc[oi].z + bb); w.w = (f16)(acc[oi].w + bb);
            *(f16x4*)&vb[((size_t)b * Cch + o) * Nn + n0 + tn * 4] = w;
        }
    } else {
        // transposed fp16: y_t[b][h][n][d], h = blockIdx.y, d = to*4..+3
        f16* yt = (p == 0) ? qt : kt;
        const int h = blockIdx.y;
        #pragma unroll
        for (int ni = 0; ni < 4; ni++) {
            f16x4 w;
            w.x = (f16)(fc(acc[0], ni) + b0);
            w.y = (f16)(fc(acc[1], ni) + b1);
            w.z = (f16)(fc(acc[2], ni) + b2);
            w.w = (f16)(fc(acc[3], ni) + b3);
            const int n = n0 + tn * 4 + ni;
            *(f16x4*)&yt[(((size_t)b * NH + h) * Nn + n) * Dh + to * 4] = w;
        }
    }
}

// ---------------------------------------------------------------------------
// rel_t[h][n][d] = f16(rel_h[h][d][n&31] + rel_w[h][d][n>>5])
// ---------------------------------------------------------------------------
__global__ __launch_bounds__(256) void relt_kernel(
    const float* __restrict__ rel_h, const float* __restrict__ rel_w,
    f16* __restrict__ rel_t)
{
    const int idx = blockIdx.x * 256 + threadIdx.x;   // NH*Nn*Dh = 262144
    const int d = idx & 63;
    const int n = (idx >> 6) & (Nn - 1);
    const int h = idx >> 16;
    const int hd = h * 64 + d;
    rel_t[idx] = (f16)(rel_h[hd * 32 + (n & 31)] + rel_w[hd * 32 + (n >> 5)]);
}

// ---------------------------------------------------------------------------
// Flash attention with fp16 MFMA.
//   S[i,j] = sum_{dd<128} Qa[i][dd]*Ka[j][dd], Qa=[q;rel], Ka=[k;q]  (K=128)
//   online softmax over j; O^T[i,d] += P[i,:] V^T (K=64)
// block = 256 (4 waves x 16 query rows), grid = (N/64, NH, B)
// ---------------------------------------------------------------------------
__global__ __launch_bounds__(256) void attn_mfma(
    const f16* __restrict__ qt, const f16* __restrict__ kt,
    const f16* __restrict__ relt, const f16* __restrict__ vb,
    float* __restrict__ out)
{
    const int i0 = blockIdx.x * BI;
    const int h  = blockIdx.y;
    const int b  = blockIdx.z;
    const int bh = b * NH + h;

    const f16* qtb = qt  + (size_t)bh * Nn * Dh;            // [n][64]
    const f16* ktb = kt  + (size_t)bh * Nn * Dh;            // [n][64]
    const f16* rlt = relt + (size_t)h * Nn * Dh;            // [n][64]
    const f16* vbb = vb  + (size_t)(b * Cch + h * Dh) * Nn; // [d][1024]

    constexpr int QS = 136;  // row stride (f16) for 128-wide tiles (+8 pad)
    constexpr int VS = 72;   // row stride for 64-wide tiles (+8 pad)
    __shared__ f16 Qa_s[64 * QS];  // 17 KB
    __shared__ f16 Ka_s[64 * QS];  // 17 KB
    __shared__ f16 v_s [64 * VS];  //  9 KB
    __shared__ f16 Pt_s[64 * VS];  //  9 KB

    const int t    = threadIdx.x;
    const int wave = t >> 6;
    const int lane = t & 63;
    const int l16  = lane & 15;
    const int quad = lane >> 4;

    // ---- stage Qa = [q | rel] once: 64 rows x 128 f16 ----
    #pragma unroll
    for (int rep = 0; rep < 4; rep++) {
        const int e   = t + rep * 256;       // 16B chunk id
        const int row = e >> 4;
        const int c8  = e & 15;
        const f16* src = (c8 < 8)
            ? &qtb[(size_t)(i0 + row) * Dh + c8 * 8]
            : &rlt[(size_t)(i0 + row) * Dh + (c8 - 8) * 8];
        *(f16x8*)&Qa_s[row * QS + c8 * 8] = *(const f16x8*)src;
    }

    f32x4 Of[4];
    #pragma unroll
    for (int ds = 0; ds < 4; ds++) Of[ds] = (f32x4){0.f, 0.f, 0.f, 0.f};
    float m_r[4], l_r[4];
    #pragma unroll
    for (int r = 0; r < 4; r++) { m_r[r] = -1e30f; l_r[r] = 0.f; }

    for (int j0 = 0; j0 < Nn; j0 += BJ) {
        // global -> regs (overlaps with other waves' compute)
        f16x8 kreg[4], vreg[2];
        #pragma unroll
        for (int rep = 0; rep < 4; rep++) {
            const int e   = t + rep * 256;
            const int row = e >> 4;
            const int c8  = e & 15;
            const f16* src = (c8 < 8)
                ? &ktb[(size_t)(j0 + row) * Dh + c8 * 8]
                : &qtb[(size_t)(j0 + row) * Dh + (c8 - 8) * 8];
            kreg[rep] = *(const f16x8*)src;
        }
        #pragma unroll
        for (int rep = 0; rep < 2; rep++) {
            const int e   = t + rep * 256;
            const int row = e >> 3;
            const int c8  = e & 7;
            vreg[rep] = *(const f16x8*)&vbb[(size_t)row * Nn + j0 + c8 * 8];
        }

        __syncthreads();   // prior iter's LDS reads complete
        #pragma unroll
        for (int rep = 0; rep < 4; rep++) {
            const int e = t + rep * 256;
            *(f16x8*)&Ka_s[(e >> 4) * QS + (e & 15) * 8] = kreg[rep];
        }
        #pragma unroll
        for (int rep = 0; rep < 2; rep++) {
            const int e = t + rep * 256;
            *(f16x8*)&v_s[(e >> 3) * VS + (e & 7) * 8] = vreg[rep];
        }
        __syncthreads();

        // ---- S = Qa^T Ka : wave computes 16(i) x 64(j), K=128 ----
        f32x4 Sf[4];
        #pragma unroll
        for (int js = 0; js < 4; js++) Sf[js] = (f32x4){0.f, 0.f, 0.f, 0.f};
        #pragma unroll
        for (int k = 0; k < 4; k++) {
            f16x8 a = *(f16x8*)&Qa_s[(wave * 16 + l16) * QS + k * 32 + quad * 8];
            #pragma unroll
            for (int js = 0; js < 4; js++) {
                f16x8 bb = *(f16x8*)&Ka_s[(js * 16 + l16) * QS + k * 32 + quad * 8];
                Sf[js] = __builtin_amdgcn_mfma_f32_16x16x32_f16(a, bb, Sf[js], 0, 0, 0);
            }
        }

        // ---- online softmax; rows i = i0 + wave*16 + quad*4 + r ----
        #pragma unroll
        for (int r = 0; r < 4; r++) {
            float tm = fmaxf(fmaxf(Sf[0][r], Sf[1][r]), fmaxf(Sf[2][r], Sf[3][r]));
            tm = fmaxf(tm, __shfl_xor(tm, 1));
            tm = fmaxf(tm, __shfl_xor(tm, 2));
            tm = fmaxf(tm, __shfl_xor(tm, 4));
            tm = fmaxf(tm, __shfl_xor(tm, 8));
            const float mnew  = fmaxf(m_r[r], tm);
            const float alpha = __expf(m_r[r] - mnew);
            m_r[r] = mnew;
            float p0 = __expf(Sf[0][r] - mnew);
            float p1 = __expf(Sf[1][r] - mnew);
            float p2 = __expf(Sf[2][r] - mnew);
            float p3 = __expf(Sf[3][r] - mnew);
            float rs = p0 + p1 + p2 + p3;
            rs += __shfl_xor(rs, 1);
            rs += __shfl_xor(rs, 2);
            rs += __shfl_xor(rs, 4);
            rs += __shfl_xor(rs, 8);
            l_r[r] = l_r[r] * alpha + rs;

            const int irow = wave * 16 + quad * 4 + r;
            Pt_s[irow * VS +  0 + l16] = (f16)p0;
            Pt_s[irow * VS + 16 + l16] = (f16)p1;
            Pt_s[irow * VS + 32 + l16] = (f16)p2;
            Pt_s[irow * VS + 48 + l16] = (f16)p3;
            #pragma unroll
            for (int ds = 0; ds < 4; ds++) Of[ds][r] *= alpha;
        }
        // Pt rows are wave-private: no barrier needed (in-wave LDS ordering)

        // ---- O^T += P V^T : 16(i) x 64(d), K=64 ----
        #pragma unroll
        for (int ks = 0; ks < 2; ks++) {
            f16x8 pa = *(f16x8*)&Pt_s[(wave * 16 + l16) * VS + ks * 32 + quad * 8];
            #pragma unroll
            for (int ds = 0; ds < 4; ds++) {
                f16x8 vv = *(f16x8*)&v_s[(ds * 16 + l16) * VS + ks * 32 + quad * 8];
                Of[ds] = __builtin_amdgcn_mfma_f32_16x16x32_f16(pa, vv, Of[ds], 0, 0, 0);
            }
        }
    }

    // ---- epilogue: out[b][h*64+d][i] = O/l ----
    #pragma unroll
    for (int r = 0; r < 4; r++) {
        const float inv = 1.0f / l_r[r];
        const int i = i0 + wave * 16 + quad * 4 + r;
        #pragma unroll
        for (int ds = 0; ds < 4; ds++) {
            const int d = ds * 16 + l16;
            out[((size_t)(b * Cch + h * Dh + d)) * Nn + i] = Of[ds][r] * inv;
        }
    }
}

// ---------------------------------------------------------------------------
extern "C" void kernel_launch(void* const* d_in, const int* in_sizes, int n_in,
                              void* d_out, int out_size, void* d_ws, size_t ws_size,
                              hipStream_t stream)
{
    const float* x     = (const float*)d_in[0];
    const float* Wq    = (const float*)d_in[1];
    const float* bq    = (const float*)d_in[2];
    const float* Wk    = (const float*)d_in[3];
    const float* bk    = (const float*)d_in[4];
    const float* Wv    = (const float*)d_in[5];
    const float* bv    = (const float*)d_in[6];
    const float* rel_h = (const float*)d_in[7];
    const float* rel_w = (const float*)d_in[8];

    f16* ws = (f16*)d_ws;
    const size_t SZQ = (size_t)Bb * NH * Nn * Dh;    // 4 Mi elems
    f16* qt   = ws;                                  // 8 MB
    f16* kt   = ws + SZQ;                            // 8 MB
    f16* vbuf = ws + 2 * SZQ;                        // 8 MB
    f16* relt = ws + 3 * SZQ;                        // 0.5 MB
    // total ws: 24.5 MB

    proj_kernel<<<dim3(Nn / 64, Cch / 64, 3 * Bb), 256, 0, stream>>>(
        x, Wq, bq, Wk, bk, Wv, bv, qt, kt, vbuf);
    relt_kernel<<<dim3((NH * Nn * Dh) / 256), 256, 0, stream>>>(rel_h, rel_w, relt);
    attn_mfma<<<dim3(Nn / BI, NH, Bb), 256, 0, stream>>>(
        qt, kt, relt, vbuf, (float*)d_out);
}

// Round 4
// 185.591 us; speedup vs baseline: 5.3507x; 1.3771x over previous
//
#include <hip/hip_runtime.h>

// B=16, C=256, HEADS=4, d=64, N=W*H=1024
constexpr int Bb  = 16;
constexpr int Cch = 256;
constexpr int NH  = 4;
constexpr int Dh  = 64;
constexpr int Nn  = 1024;
constexpr int BI  = 64;     // attn: query rows per block
constexpr int BJ  = 64;     // attn: key tile

typedef _Float16 f16;
typedef __attribute__((ext_vector_type(8))) _Float16 f16x8;
typedef __attribute__((ext_vector_type(4))) _Float16 f16x4;
typedef __attribute__((ext_vector_type(4))) float    f32x4;

// ---------------------------------------------------------------------------
// Cast stacked weights to fp16: Wh[p*256+o][c] for p in {q,k,v}
// ---------------------------------------------------------------------------
__global__ __launch_bounds__(256) void wcast_kernel(
    const float* __restrict__ Wq, const float* __restrict__ Wk,
    const float* __restrict__ Wv, f16* __restrict__ Wh)
{
    const int idx = blockIdx.x * 256 + threadIdx.x;   // 768*256 = 196608
    const int og  = idx >> 8;        // 0..767
    const int c   = idx & 255;
    const int p   = og >> 8;
    const int o   = og & 255;
    const float* W = (p == 0) ? Wq : (p == 1) ? Wk : Wv;
    Wh[idx] = (f16)W[o * 256 + c];
}

// ---------------------------------------------------------------------------
// Transpose+cast: xt[b][n][c] = f16(x[b][c][n]). 64x64 LDS tiles.
// grid = (N/64, C/64, B)
// ---------------------------------------------------------------------------
__global__ __launch_bounds__(256) void xtrans_kernel(
    const float* __restrict__ x, f16* __restrict__ xt)
{
    const int n0 = blockIdx.x * 64;
    const int c0 = blockIdx.y * 64;
    const int b  = blockIdx.z;
    __shared__ float T[64][65];
    const int t = threadIdx.x;

    #pragma unroll
    for (int rep = 0; rep < 16; rep++) {
        const int e  = t + rep * 256;
        const int r  = e >> 6;    // c
        const int cc = e & 63;    // n
        T[r][cc] = x[((size_t)b * Cch + c0 + r) * Nn + n0 + cc];
    }
    __syncthreads();
    #pragma unroll
    for (int rep = 0; rep < 4; rep++) {
        const int e  = t + rep * 256;      // 8B chunk id, 1024 total
        const int nn = e >> 4;
        const int c4 = e & 15;
        f16x4 w;
        w.x = (f16)T[c4 * 4 + 0][nn];
        w.y = (f16)T[c4 * 4 + 1][nn];
        w.z = (f16)T[c4 * 4 + 2][nn];
        w.w = (f16)T[c4 * 4 + 3][nn];
        *(f16x4*)&xt[((size_t)b * Nn + n0 + nn) * Cch + c0 + c4 * 4] = w;
    }
}

// ---------------------------------------------------------------------------
// rel_t[h][n][d] = f16(rel_h[h][d][n&31] + rel_w[h][d][n>>5])
// ---------------------------------------------------------------------------
__global__ __launch_bounds__(256) void relt_kernel(
    const float* __restrict__ rel_h, const float* __restrict__ rel_w,
    f16* __restrict__ rel_t)
{
    const int idx = blockIdx.x * 256 + threadIdx.x;   // NH*Nn*Dh = 262144
    const int d = idx & 63;
    const int n = (idx >> 6) & (Nn - 1);
    const int h = idx >> 16;
    const int hd = h * 64 + d;
    rel_t[idx] = (f16)(rel_h[hd * 32 + (n & 31)] + rel_w[hd * 32 + (n >> 5)]);
}

// ---------------------------------------------------------------------------
// QKV projection GEMM, fp16 MFMA.
//   p<2 : D[o][n] = W·x    (A = Wh rows o, B = xt rows n)
//   p==2: D[n][c] = x^T·W^T (A = xt rows n, B = Wh rows c)  — operand swap so
//         every case stores D via f16x4 along its fast output axis.
// grid = (8 n-tiles, 6 o-tiles over 768, B); block = 256 (4 waves, 2x2)
// ---------------------------------------------------------------------------
__global__ __launch_bounds__(256) void gemm_qkv(
    const f16* __restrict__ Wh, const f16* __restrict__ xt,
    const float* __restrict__ bq, const float* __restrict__ bk,
    const float* __restrict__ bv,
    f16* __restrict__ qt, f16* __restrict__ kt, f16* __restrict__ vb)
{
    const int bx   = blockIdx.x;       // n-tile
    const int y    = blockIdx.y;       // o-tile over 768
    const int b    = blockIdx.z;
    const int p    = y >> 1;           // 0=q,1=k,2=v
    const int half = y & 1;

    constexpr int ST = 40;             // LDS row stride (f16), 32 + 8 pad
    __shared__ f16 Wt[128 * ST];
    __shared__ f16 Xt[128 * ST];

    const int t    = threadIdx.x;
    const int wave = t >> 6;
    const int lane = t & 63;
    const int l16  = lane & 15;
    const int quad = lane >> 4;
    const int wm   = wave >> 1;        // m-half
    const int wsd  = wave & 1;         // s-half

    f32x4 acc[4][4];
    #pragma unroll
    for (int mi = 0; mi < 4; mi++)
        #pragma unroll
        for (int ni = 0; ni < 4; ni++) acc[mi][ni] = (f32x4){0.f, 0.f, 0.f, 0.f};

    const f16* Wg = Wh + (size_t)y * 128 * 256;
    const f16* Xg = xt + ((size_t)b * Nn + bx * 128) * 256;

    for (int c0 = 0; c0 < 256; c0 += 32) {
        f16x8 wch[2], xch[2];
        #pragma unroll
        for (int rep = 0; rep < 2; rep++) {
            const int e   = t + rep * 256;
            const int row = e >> 2;
            const int c8  = e & 3;
            wch[rep] = *(const f16x8*)&Wg[(size_t)row * 256 + c0 + c8 * 8];
            xch[rep] = *(const f16x8*)&Xg[(size_t)row * 256 + c0 + c8 * 8];
        }
        __syncthreads();
        #pragma unroll
        for (int rep = 0; rep < 2; rep++) {
            const int e   = t + rep * 256;
            const int row = e >> 2;
            const int c8  = e & 3;
            *(f16x8*)&Wt[row * ST + c8 * 8] = wch[rep];
            *(f16x8*)&Xt[row * ST + c8 * 8] = xch[rep];
        }
        __syncthreads();

        const f16* tf = (p < 2) ? Wt : Xt;   // m-operand tile
        const f16* ts = (p < 2) ? Xt : Wt;   // s-operand tile
        f16x8 af[4], bf[4];
        #pragma unroll
        for (int mi = 0; mi < 4; mi++)
            af[mi] = *(const f16x8*)&tf[(wm * 64 + mi * 16 + l16) * ST + quad * 8];
        #pragma unroll
        for (int ni = 0; ni < 4; ni++)
            bf[ni] = *(const f16x8*)&ts[(wsd * 64 + ni * 16 + l16) * ST + quad * 8];
        #pragma unroll
        for (int mi = 0; mi < 4; mi++)
            #pragma unroll
            for (int ni = 0; ni < 4; ni++)
                acc[mi][ni] = __builtin_amdgcn_mfma_f32_16x16x32_f16(
                    af[mi], bf[ni], acc[mi][ni], 0, 0, 0);
    }

    // ---- epilogue: bias (fp32) + direct f16x4 stores ----
    if (p < 2) {
        // D[m=o][s=n]; lane holds 4 consecutive o (=d) at fixed n
        f16* yt = (p == 0) ? qt : kt;
        const float* bg = (p == 0) ? bq : bk;
        #pragma unroll
        for (int mi = 0; mi < 4; mi++) {
            const int o_in = half * 128 + wm * 64 + mi * 16 + quad * 4;
            const float4 b4 = *(const float4*)&bg[o_in];
            const int h = o_in >> 6;
            const int d = o_in & 63;
            #pragma unroll
            for (int ni = 0; ni < 4; ni++) {
                const int n = bx * 128 + wsd * 64 + ni * 16 + l16;
                f16x4 w;
                w.x = (f16)(acc[mi][ni][0] + b4.x);
                w.y = (f16)(acc[mi][ni][1] + b4.y);
                w.z = (f16)(acc[mi][ni][2] + b4.z);
                w.w = (f16)(acc[mi][ni][3] + b4.w);
                *(f16x4*)&yt[(((size_t)b * NH + h) * Nn + n) * Dh + d] = w;
            }
        }
    } else {
        // D[m=n][s=c]; lane holds 4 consecutive n at fixed c
        #pragma unroll
        for (int ni = 0; ni < 4; ni++) {
            const int c  = half * 128 + wsd * 64 + ni * 16 + l16;
            const float bs = bv[c];
            #pragma unroll
            for (int mi = 0; mi < 4; mi++) {
                const int n = bx * 128 + wm * 64 + mi * 16 + quad * 4;
                f16x4 w;
                w.x = (f16)(acc[mi][ni][0] + bs);
                w.y = (f16)(acc[mi][ni][1] + bs);
                w.z = (f16)(acc[mi][ni][2] + bs);
                w.w = (f16)(acc[mi][ni][3] + bs);
                *(f16x4*)&vb[((size_t)b * Cch + c) * Nn + n] = w;
            }
        }
    }
}

// ---------------------------------------------------------------------------
// Flash attention with fp16 MFMA (unchanged from round 3).
// ---------------------------------------------------------------------------
__global__ __launch_bounds__(256) void attn_mfma(
    const f16* __restrict__ qt, const f16* __restrict__ kt,
    const f16* __restrict__ relt, const f16* __restrict__ vb,
    float* __restrict__ out)
{
    const int i0 = blockIdx.x * BI;
    const int h  = blockIdx.y;
    const int b  = blockIdx.z;
    const int bh = b * NH + h;

    const f16* qtb = qt  + (size_t)bh * Nn * Dh;            // [n][64]
    const f16* ktb = kt  + (size_t)bh * Nn * Dh;            // [n][64]
    const f16* rlt = relt + (size_t)h * Nn * Dh;            // [n][64]
    const f16* vbb = vb  + (size_t)(b * Cch + h * Dh) * Nn; // [d][1024]

    constexpr int QS = 136;
    constexpr int VS = 72;
    __shared__ f16 Qa_s[64 * QS];
    __shared__ f16 Ka_s[64 * QS];
    __shared__ f16 v_s [64 * VS];
    __shared__ f16 Pt_s[64 * VS];

    const int t    = threadIdx.x;
    const int wave = t >> 6;
    const int lane = t & 63;
    const int l16  = lane & 15;
    const int quad = lane >> 4;

    #pragma unroll
    for (int rep = 0; rep < 4; rep++) {
        const int e   = t + rep * 256;
        const int row = e >> 4;
        const int c8  = e & 15;
        const f16* src = (c8 < 8)
            ? &qtb[(size_t)(i0 + row) * Dh + c8 * 8]
            : &rlt[(size_t)(i0 + row) * Dh + (c8 - 8) * 8];
        *(f16x8*)&Qa_s[row * QS + c8 * 8] = *(const f16x8*)src;
    }

    f32x4 Of[4];
    #pragma unroll
    for (int ds = 0; ds < 4; ds++) Of[ds] = (f32x4){0.f, 0.f, 0.f, 0.f};
    float m_r[4], l_r[4];
    #pragma unroll
    for (int r = 0; r < 4; r++) { m_r[r] = -1e30f; l_r[r] = 0.f; }

    for (int j0 = 0; j0 < Nn; j0 += BJ) {
        f16x8 kreg[4], vreg[2];
        #pragma unroll
        for (int rep = 0; rep < 4; rep++) {
            const int e   = t + rep * 256;
            const int row = e >> 4;
            const int c8  = e & 15;
            const f16* src = (c8 < 8)
                ? &ktb[(size_t)(j0 + row) * Dh + c8 * 8]
                : &qtb[(size_t)(j0 + row) * Dh + (c8 - 8) * 8];
            kreg[rep] = *(const f16x8*)src;
        }
        #pragma unroll
        for (int rep = 0; rep < 2; rep++) {
            const int e   = t + rep * 256;
            const int row = e >> 3;
            const int c8  = e & 7;
            vreg[rep] = *(const f16x8*)&vbb[(size_t)row * Nn + j0 + c8 * 8];
        }

        __syncthreads();
        #pragma unroll
        for (int rep = 0; rep < 4; rep++) {
            const int e = t + rep * 256;
            *(f16x8*)&Ka_s[(e >> 4) * QS + (e & 15) * 8] = kreg[rep];
        }
        #pragma unroll
        for (int rep = 0; rep < 2; rep++) {
            const int e = t + rep * 256;
            *(f16x8*)&v_s[(e >> 3) * VS + (e & 7) * 8] = vreg[rep];
        }
        __syncthreads();

        f32x4 Sf[4];
        #pragma unroll
        for (int js = 0; js < 4; js++) Sf[js] = (f32x4){0.f, 0.f, 0.f, 0.f};
        #pragma unroll
        for (int k = 0; k < 4; k++) {
            f16x8 a = *(f16x8*)&Qa_s[(wave * 16 + l16) * QS + k * 32 + quad * 8];
            #pragma unroll
            for (int js = 0; js < 4; js++) {
                f16x8 bb = *(f16x8*)&Ka_s[(js * 16 + l16) * QS + k * 32 + quad * 8];
                Sf[js] = __builtin_amdgcn_mfma_f32_16x16x32_f16(a, bb, Sf[js], 0, 0, 0);
            }
        }

        #pragma unroll
        for (int r = 0; r < 4; r++) {
            float tm = fmaxf(fmaxf(Sf[0][r], Sf[1][r]), fmaxf(Sf[2][r], Sf[3][r]));
            tm = fmaxf(tm, __shfl_xor(tm, 1));
            tm = fmaxf(tm, __shfl_xor(tm, 2));
            tm = fmaxf(tm, __shfl_xor(tm, 4));
            tm = fmaxf(tm, __shfl_xor(tm, 8));
            const float mnew  = fmaxf(m_r[r], tm);
            const float alpha = __expf(m_r[r] - mnew);
            m_r[r] = mnew;
            float p0 = __expf(Sf[0][r] - mnew);
            float p1 = __expf(Sf[1][r] - mnew);
            float p2 = __expf(Sf[2][r] - mnew);
            float p3 = __expf(Sf[3][r] - mnew);
            float rs = p0 + p1 + p2 + p3;
            rs += __shfl_xor(rs, 1);
            rs += __shfl_xor(rs, 2);
            rs += __shfl_xor(rs, 4);
            rs += __shfl_xor(rs, 8);
            l_r[r] = l_r[r] * alpha + rs;

            const int irow = wave * 16 + quad * 4 + r;
            Pt_s[irow * VS +  0 + l16] = (f16)p0;
            Pt_s[irow * VS + 16 + l16] = (f16)p1;
            Pt_s[irow * VS + 32 + l16] = (f16)p2;
            Pt_s[irow * VS + 48 + l16] = (f16)p3;
            #pragma unroll
            for (int ds = 0; ds < 4; ds++) Of[ds][r] *= alpha;
        }

        #pragma unroll
        for (int ks = 0; ks < 2; ks++) {
            f16x8 pa = *(f16x8*)&Pt_s[(wave * 16 + l16) * VS + ks * 32 + quad * 8];
            #pragma unroll
            for (int ds = 0; ds < 4; ds++) {
                f16x8 vv = *(f16x8*)&v_s[(ds * 16 + l16) * VS + ks * 32 + quad * 8];
                Of[ds] = __builtin_amdgcn_mfma_f32_16x16x32_f16(pa, vv, Of[ds], 0, 0, 0);
            }
        }
    }

    #pragma unroll
    for (int r = 0; r < 4; r++) {
        const float inv = 1.0f / l_r[r];
        const int i = i0 + wave * 16 + quad * 4 + r;
        #pragma unroll
        for (int ds = 0; ds < 4; ds++) {
            const int d = ds * 16 + l16;
            out[((size_t)(b * Cch + h * Dh + d)) * Nn + i] = Of[ds][r] * inv;
        }
    }
}

// ---------------------------------------------------------------------------
extern "C" void kernel_launch(void* const* d_in, const int* in_sizes, int n_in,
                              void* d_out, int out_size, void* d_ws, size_t ws_size,
                              hipStream_t stream)
{
    const float* x     = (const float*)d_in[0];
    const float* Wq    = (const float*)d_in[1];
    const float* bq    = (const float*)d_in[2];
    const float* Wk    = (const float*)d_in[3];
    const float* bk    = (const float*)d_in[4];
    const float* Wv    = (const float*)d_in[5];
    const float* bv    = (const float*)d_in[6];
    const float* rel_h = (const float*)d_in[7];
    const float* rel_w = (const float*)d_in[8];

    f16* ws = (f16*)d_ws;
    const size_t SZQ = (size_t)Bb * NH * Nn * Dh;    // 4 Mi elems
    f16* qt   = ws;                                  // 8 MB
    f16* kt   = ws + SZQ;                            // 8 MB
    f16* vbuf = ws + 2 * SZQ;                        // 8 MB
    f16* relt = ws + 3 * SZQ;                        // 0.5 MB
    f16* xth  = ws + 3 * SZQ + (size_t)NH * Nn * Dh; // 8 MB  [b][n][c]
    f16* Wh   = xth + SZQ;                           // 0.4 MB [768][256]
    // total ws: ~33 MB

    wcast_kernel<<<dim3((3 * Cch * Cch) / 256), 256, 0, stream>>>(Wq, Wk, Wv, Wh);
    xtrans_kernel<<<dim3(Nn / 64, Cch / 64, Bb), 256, 0, stream>>>(x, xth);
    relt_kernel<<<dim3((NH * Nn * Dh) / 256), 256, 0, stream>>>(rel_h, rel_w, relt);
    gemm_qkv<<<dim3(Nn / 128, 6, Bb), 256, 0, stream>>>(
        Wh, xth, bq, bk, bv, qt, kt, vbuf);
    attn_mfma<<<dim3(Nn / BI, NH, Bb), 256, 0, stream>>>(
        qt, kt, relt, vbuf, (float*)d_out);
}

// Round 5
// 157.593 us; speedup vs baseline: 6.3014x; 1.1777x over previous
//
#include <hip/hip_runtime.h>

// B=16, C=256, HEADS=4, d=64, N=W*H=1024
constexpr int Bb  = 16;
constexpr int Cch = 256;
constexpr int NH  = 4;
constexpr int Dh  = 64;
constexpr int Nn  = 1024;

typedef _Float16 f16;
typedef __attribute__((ext_vector_type(8))) _Float16 f16x8;
typedef __attribute__((ext_vector_type(4))) _Float16 f16x4;
typedef __attribute__((ext_vector_type(4))) float    f32x4;

// ---------------------------------------------------------------------------
// Fused prep: xtrans (blocks 0..1023) | relt (1024..2047) | wcast (2048..2815)
// ---------------------------------------------------------------------------
__global__ __launch_bounds__(256) void prep_kernel(
    const float* __restrict__ x,
    const float* __restrict__ Wq, const float* __restrict__ Wk,
    const float* __restrict__ Wv,
    const float* __restrict__ rel_h, const float* __restrict__ rel_w,
    f16* __restrict__ xt, f16* __restrict__ Wh, f16* __restrict__ rel_t)
{
    const int gx = blockIdx.x;
    const int t  = threadIdx.x;
    __shared__ float T[64][65];

    if (gx < 1024) {
        // xt[b][n][c] = f16(x[b][c][n]), 64x64 LDS transpose tiles
        const int n0 = (gx & 15) * 64;
        const int c0 = ((gx >> 4) & 3) * 64;
        const int b  = gx >> 6;
        #pragma unroll
        for (int rep = 0; rep < 16; rep++) {
            const int e  = t + rep * 256;
            const int r  = e >> 6;    // c
            const int cc = e & 63;    // n
            T[r][cc] = x[((size_t)b * Cch + c0 + r) * Nn + n0 + cc];
        }
        __syncthreads();
        #pragma unroll
        for (int rep = 0; rep < 4; rep++) {
            const int e  = t + rep * 256;
            const int nn = e >> 4;
            const int c4 = e & 15;
            f16x4 w;
            w.x = (f16)T[c4 * 4 + 0][nn];
            w.y = (f16)T[c4 * 4 + 1][nn];
            w.z = (f16)T[c4 * 4 + 2][nn];
            w.w = (f16)T[c4 * 4 + 3][nn];
            *(f16x4*)&xt[((size_t)b * Nn + n0 + nn) * Cch + c0 + c4 * 4] = w;
        }
    } else if (gx < 2048) {
        // rel_t[h][n][d] = f16(rel_h[h][d][n&31] + rel_w[h][d][n>>5])
        const int idx = (gx - 1024) * 256 + t;     // NH*Nn*Dh = 262144
        const int d = idx & 63;
        const int n = (idx >> 6) & (Nn - 1);
        const int h = idx >> 16;
        const int hd = h * 64 + d;
        rel_t[idx] = (f16)(rel_h[hd * 32 + (n & 31)] + rel_w[hd * 32 + (n >> 5)]);
    } else {
        // Wh[p*256+o][c] = f16(W[o][c])
        const int idx = (gx - 2048) * 256 + t;     // 768*256 = 196608
        const int og  = idx >> 8;
        const int c   = idx & 255;
        const int p   = og >> 8;
        const int o   = og & 255;
        const float* W = (p == 0) ? Wq : (p == 1) ? Wk : Wv;
        Wh[idx] = (f16)W[o * 256 + c];
    }
}

// ---------------------------------------------------------------------------
// QKV projection GEMM, fp16 MFMA (unchanged from round 4; ST=40 is
// conflict-free: 20 dwords ≡ 20 mod 32 spreads all 8 bank-groups).
// ---------------------------------------------------------------------------
__global__ __launch_bounds__(256) void gemm_qkv(
    const f16* __restrict__ Wh, const f16* __restrict__ xt,
    const float* __restrict__ bq, const float* __restrict__ bk,
    const float* __restrict__ bv,
    f16* __restrict__ qt, f16* __restrict__ kt, f16* __restrict__ vb)
{
    const int bx   = blockIdx.x;
    const int y    = blockIdx.y;
    const int b    = blockIdx.z;
    const int p    = y >> 1;
    const int half = y & 1;

    constexpr int ST = 40;
    __shared__ f16 Wt[128 * ST];
    __shared__ f16 Xt[128 * ST];

    const int t    = threadIdx.x;
    const int wave = t >> 6;
    const int lane = t & 63;
    const int l16  = lane & 15;
    const int quad = lane >> 4;
    const int wm   = wave >> 1;
    const int wsd  = wave & 1;

    f32x4 acc[4][4];
    #pragma unroll
    for (int mi = 0; mi < 4; mi++)
        #pragma unroll
        for (int ni = 0; ni < 4; ni++) acc[mi][ni] = (f32x4){0.f, 0.f, 0.f, 0.f};

    const f16* Wg = Wh + (size_t)y * 128 * 256;
    const f16* Xg = xt + ((size_t)b * Nn + bx * 128) * 256;

    for (int c0 = 0; c0 < 256; c0 += 32) {
        f16x8 wch[2], xch[2];
        #pragma unroll
        for (int rep = 0; rep < 2; rep++) {
            const int e   = t + rep * 256;
            const int row = e >> 2;
            const int c8  = e & 3;
            wch[rep] = *(const f16x8*)&Wg[(size_t)row * 256 + c0 + c8 * 8];
            xch[rep] = *(const f16x8*)&Xg[(size_t)row * 256 + c0 + c8 * 8];
        }
        __syncthreads();
        #pragma unroll
        for (int rep = 0; rep < 2; rep++) {
            const int e   = t + rep * 256;
            const int row = e >> 2;
            const int c8  = e & 3;
            *(f16x8*)&Wt[row * ST + c8 * 8] = wch[rep];
            *(f16x8*)&Xt[row * ST + c8 * 8] = xch[rep];
        }
        __syncthreads();

        const f16* tf = (p < 2) ? Wt : Xt;
        const f16* ts = (p < 2) ? Xt : Wt;
        f16x8 af[4], bf[4];
        #pragma unroll
        for (int mi = 0; mi < 4; mi++)
            af[mi] = *(const f16x8*)&tf[(wm * 64 + mi * 16 + l16) * ST + quad * 8];
        #pragma unroll
        for (int ni = 0; ni < 4; ni++)
            bf[ni] = *(const f16x8*)&ts[(wsd * 64 + ni * 16 + l16) * ST + quad * 8];
        #pragma unroll
        for (int mi = 0; mi < 4; mi++)
            #pragma unroll
            for (int ni = 0; ni < 4; ni++)
                acc[mi][ni] = __builtin_amdgcn_mfma_f32_16x16x32_f16(
                    af[mi], bf[ni], acc[mi][ni], 0, 0, 0);
    }

    if (p < 2) {
        f16* yt = (p == 0) ? qt : kt;
        const float* bg = (p == 0) ? bq : bk;
        #pragma unroll
        for (int mi = 0; mi < 4; mi++) {
            const int o_in = half * 128 + wm * 64 + mi * 16 + quad * 4;
            const float4 b4 = *(const float4*)&bg[o_in];
            const int h = o_in >> 6;
            const int d = o_in & 63;
            #pragma unroll
            for (int ni = 0; ni < 4; ni++) {
                const int n = bx * 128 + wsd * 64 + ni * 16 + l16;
                f16x4 w;
                w.x = (f16)(acc[mi][ni][0] + b4.x);
                w.y = (f16)(acc[mi][ni][1] + b4.y);
                w.z = (f16)(acc[mi][ni][2] + b4.z);
                w.w = (f16)(acc[mi][ni][3] + b4.w);
                *(f16x4*)&yt[(((size_t)b * NH + h) * Nn + n) * Dh + d] = w;
            }
        }
    } else {
        #pragma unroll
        for (int ni = 0; ni < 4; ni++) {
            const int c  = half * 128 + wsd * 64 + ni * 16 + l16;
            const float bs = bv[c];
            #pragma unroll
            for (int mi = 0; mi < 4; mi++) {
                const int n = bx * 128 + wm * 64 + mi * 16 + quad * 4;
                f16x4 w;
                w.x = (f16)(acc[mi][ni][0] + bs);
                w.y = (f16)(acc[mi][ni][1] + bs);
                w.z = (f16)(acc[mi][ni][2] + bs);
                w.w = (f16)(acc[mi][ni][3] + bs);
                *(f16x4*)&vb[((size_t)b * Cch + c) * Nn + n] = w;
            }
        }
    }
}

// ---------------------------------------------------------------------------
// Flash attention, fp16 MFMA, XOR-swizzled LDS (no padding, conflict-free).
// BI=128 (4 waves x 32 query rows), BJ=64. A-frags of Qa hoisted (j-invariant).
// Row-sum l computed via MFMA with a ones B-fragment.
// grid = (N/128, NH, B), block = 256.
// ---------------------------------------------------------------------------
__global__ __launch_bounds__(256, 2) void attn_mfma(
    const f16* __restrict__ qt, const f16* __restrict__ kt,
    const f16* __restrict__ relt, const f16* __restrict__ vb,
    float* __restrict__ out)
{
    const int i0 = blockIdx.x * 128;
    const int h  = blockIdx.y;
    const int b  = blockIdx.z;
    const int bh = b * NH + h;

    const f16* qtb = qt  + (size_t)bh * Nn * Dh;            // [n][64]
    const f16* ktb = kt  + (size_t)bh * Nn * Dh;            // [n][64]
    const f16* rlt = relt + (size_t)h * Nn * Dh;            // [n][64]
    const f16* vbb = vb  + (size_t)(b * Cch + h * Dh) * Nn; // [d][1024]

    // XOR-swizzled tiles: elem(row, col) at row*W + ((col>>3 ^ (row&7))<<3) + (col&7)
    __shared__ f16 Qa_s[128 * 128];  // 32 KB  [i][128: q|rel]
    __shared__ f16 Ka_s[64 * 128];   // 16 KB  [j][128: k|q]
    __shared__ f16 v_s [64 * 64];    //  8 KB  [d][j]
    __shared__ f16 Pt_s[128 * 64];   // 16 KB  [i][j]

    const int t    = threadIdx.x;
    const int wave = t >> 6;
    const int lane = t & 63;
    const int l16  = lane & 15;
    const int quad = lane >> 4;

    // ---- stage Qa = [q | rel]: 128 rows x 128 f16, swizzled ----
    #pragma unroll
    for (int rep = 0; rep < 8; rep++) {
        const int e   = t + rep * 256;
        const int row = e >> 4;
        const int c8  = e & 15;
        const f16* src = (c8 < 8)
            ? &qtb[(size_t)(i0 + row) * Dh + c8 * 8]
            : &rlt[(size_t)(i0 + row) * Dh + (c8 - 8) * 8];
        *(f16x8*)&Qa_s[(row << 7) + ((c8 ^ (row & 7)) << 3)] = *(const f16x8*)src;
    }
    __syncthreads();

    // ---- hoist Qa A-fragments (j-invariant): 2 m-subtiles x 4 k-slices ----
    f16x8 af[2][4];
    #pragma unroll
    for (int ms = 0; ms < 2; ms++) {
        const int row = wave * 32 + ms * 16 + l16;
        #pragma unroll
        for (int k = 0; k < 4; k++)
            af[ms][k] = *(const f16x8*)
                &Qa_s[(row << 7) + ((((k << 2) + quad) ^ (row & 7)) << 3)];
    }

    f16x8 ones;
    #pragma unroll
    for (int u = 0; u < 8; u++) ones[u] = (f16)1.0f;

    f32x4 Of[2][4], Ol[2];
    float m_r[2][4];
    #pragma unroll
    for (int ms = 0; ms < 2; ms++) {
        Ol[ms] = (f32x4){0.f, 0.f, 0.f, 0.f};
        #pragma unroll
        for (int ds = 0; ds < 4; ds++) Of[ms][ds] = (f32x4){0.f, 0.f, 0.f, 0.f};
        #pragma unroll
        for (int r = 0; r < 4; r++) m_r[ms][r] = -1e30f;
    }

    for (int j0 = 0; j0 < Nn; j0 += 64) {
        // global -> regs
        f16x8 kreg[4], vreg[2];
        #pragma unroll
        for (int rep = 0; rep < 4; rep++) {
            const int e   = t + rep * 256;
            const int row = e >> 4;
            const int c8  = e & 15;
            const f16* src = (c8 < 8)
                ? &ktb[(size_t)(j0 + row) * Dh + c8 * 8]
                : &qtb[(size_t)(j0 + row) * Dh + (c8 - 8) * 8];
            kreg[rep] = *(const f16x8*)src;
        }
        #pragma unroll
        for (int rep = 0; rep < 2; rep++) {
            const int e   = t + rep * 256;
            const int row = e >> 3;
            const int c8  = e & 7;
            vreg[rep] = *(const f16x8*)&vbb[(size_t)row * Nn + j0 + c8 * 8];
        }

        __syncthreads();   // prior iter's Ka/v reads complete
        #pragma unroll
        for (int rep = 0; rep < 4; rep++) {
            const int e   = t + rep * 256;
            const int row = e >> 4;
            const int c8  = e & 15;
            *(f16x8*)&Ka_s[(row << 7) + ((c8 ^ (row & 7)) << 3)] = kreg[rep];
        }
        #pragma unroll
        for (int rep = 0; rep < 2; rep++) {
            const int e   = t + rep * 256;
            const int row = e >> 3;
            const int c8  = e & 7;
            *(f16x8*)&v_s[(row << 6) + ((c8 ^ (row & 7)) << 3)] = vreg[rep];
        }
        __syncthreads();

        // ---- S = Qa·Ka^T : 2x(16) rows x 64 cols, K=128 ----
        f32x4 Sf[2][4];
        #pragma unroll
        for (int ms = 0; ms < 2; ms++)
            #pragma unroll
            for (int js = 0; js < 4; js++) Sf[ms][js] = (f32x4){0.f, 0.f, 0.f, 0.f};
        #pragma unroll
        for (int k = 0; k < 4; k++) {
            f16x8 bb[4];
            #pragma unroll
            for (int js = 0; js < 4; js++) {
                const int row = js * 16 + l16;
                bb[js] = *(const f16x8*)
                    &Ka_s[(row << 7) + ((((k << 2) + quad) ^ (row & 7)) << 3)];
            }
            #pragma unroll
            for (int ms = 0; ms < 2; ms++)
                #pragma unroll
                for (int js = 0; js < 4; js++)
                    Sf[ms][js] = __builtin_amdgcn_mfma_f32_16x16x32_f16(
                        af[ms][k], bb[js], Sf[ms][js], 0, 0, 0);
        }

        // ---- online softmax (max tree only; sums via MFMA ones) ----
        #pragma unroll
        for (int ms = 0; ms < 2; ms++) {
            #pragma unroll
            for (int r = 0; r < 4; r++) {
                float tm = fmaxf(fmaxf(Sf[ms][0][r], Sf[ms][1][r]),
                                 fmaxf(Sf[ms][2][r], Sf[ms][3][r]));
                tm = fmaxf(tm, __shfl_xor(tm, 1));
                tm = fmaxf(tm, __shfl_xor(tm, 2));
                tm = fmaxf(tm, __shfl_xor(tm, 4));
                tm = fmaxf(tm, __shfl_xor(tm, 8));
                const float mnew  = fmaxf(m_r[ms][r], tm);
                const float alpha = __expf(m_r[ms][r] - mnew);
                m_r[ms][r] = mnew;

                const int row = wave * 32 + ms * 16 + quad * 4 + r;
                const int rx  = row & 7;
                #pragma unroll
                for (int js = 0; js < 4; js++) {
                    const float p = __expf(Sf[ms][js][r] - mnew);
                    const int col = js * 16 + l16;
                    Pt_s[(row << 6) + (((col >> 3) ^ rx) << 3) + (col & 7)] = (f16)p;
                }
                #pragma unroll
                for (int ds = 0; ds < 4; ds++) Of[ms][ds][r] *= alpha;
                Ol[ms][r] *= alpha;
            }
        }
        // Pt rows are wave-private: in-wave LDS ordering, no barrier

        // ---- O += P·V^T (K=64); l += P·1 ----
        #pragma unroll
        for (int ks = 0; ks < 2; ks++) {
            #pragma unroll
            for (int ms = 0; ms < 2; ms++) {
                const int prow = wave * 32 + ms * 16 + l16;
                f16x8 pa = *(const f16x8*)
                    &Pt_s[(prow << 6) + ((((ks << 2) + quad) ^ (prow & 7)) << 3)];
                #pragma unroll
                for (int ds = 0; ds < 4; ds++) {
                    const int vrow = ds * 16 + l16;
                    f16x8 vv = *(const f16x8*)
                        &v_s[(vrow << 6) + ((((ks << 2) + quad) ^ (vrow & 7)) << 3)];
                    Of[ms][ds] = __builtin_amdgcn_mfma_f32_16x16x32_f16(
                        pa, vv, Of[ms][ds], 0, 0, 0);
                }
                Ol[ms] = __builtin_amdgcn_mfma_f32_16x16x32_f16(
                    pa, ones, Ol[ms], 0, 0, 0);
            }
        }
    }

    // ---- epilogue ----
    #pragma unroll
    for (int ms = 0; ms < 2; ms++) {
        #pragma unroll
        for (int r = 0; r < 4; r++) {
            const float inv = 1.0f / Ol[ms][r];
            const int i = i0 + wave * 32 + ms * 16 + quad * 4 + r;
            #pragma unroll
            for (int ds = 0; ds < 4; ds++) {
                const int d = ds * 16 + l16;
                out[((size_t)(b * Cch + h * Dh + d)) * Nn + i] = Of[ms][ds][r] * inv;
            }
        }
    }
}

// ---------------------------------------------------------------------------
extern "C" void kernel_launch(void* const* d_in, const int* in_sizes, int n_in,
                              void* d_out, int out_size, void* d_ws, size_t ws_size,
                              hipStream_t stream)
{
    const float* x     = (const float*)d_in[0];
    const float* Wq    = (const float*)d_in[1];
    const float* bq    = (const float*)d_in[2];
    const float* Wk    = (const float*)d_in[3];
    const float* bk    = (const float*)d_in[4];
    const float* Wv    = (const float*)d_in[5];
    const float* bv    = (const float*)d_in[6];
    const float* rel_h = (const float*)d_in[7];
    const float* rel_w = (const float*)d_in[8];

    f16* ws = (f16*)d_ws;
    const size_t SZQ = (size_t)Bb * NH * Nn * Dh;    // 4 Mi elems
    f16* qt   = ws;                                  // 8 MB
    f16* kt   = ws + SZQ;                            // 8 MB
    f16* vbuf = ws + 2 * SZQ;                        // 8 MB
    f16* relt = ws + 3 * SZQ;                        // 0.5 MB
    f16* xth  = ws + 3 * SZQ + (size_t)NH * Nn * Dh; // 8 MB  [b][n][c]
    f16* Wh   = xth + SZQ;                           // 0.4 MB [768][256]

    prep_kernel<<<dim3(2816), 256, 0, stream>>>(
        x, Wq, Wk, Wv, rel_h, rel_w, xth, Wh, relt);
    gemm_qkv<<<dim3(Nn / 128, 6, Bb), 256, 0, stream>>>(
        Wh, xth, bq, bk, bv, qt, kt, vbuf);
    attn_mfma<<<dim3(Nn / 128, NH, Bb), 256, 0, stream>>>(
        qt, kt, relt, vbuf, (float*)d_out);
}